// Round 5
// baseline (352.327 us; speedup 1.0000x reference)
//
#include <hip/hip_runtime.h>
#include <math.h>

// Problem constants (from reference)
#define B_      8
#define S_      4096
#define H_      2048
#define HINT_   4
#define WS_     16
#define STRIDE_ 8
#define MLPH_   64
#define NW_     512            // windows per batch
#define WPB_    4              // windows per block (round-5: 2x blocks, 3x occupancy)
#define ROWS_   40             // rows spanned per block: 8*WPB_ + 8
#define KT_     68             // k-tiles of 32 covering K=2052 padded to 2176
#define KPAD_   2176
#define LDK_    2184           // LDS row stride in shorts (pad 8)
#define NT_     4              // n-tiles of 16 covering MLPH_=64
#define PLD_    66             // partLds row stride (floats)

typedef float  floatx4 __attribute__((ext_vector_type(4)));
typedef short  shortx8 __attribute__((ext_vector_type(8)));

__device__ __forceinline__ unsigned short f2b(float x) {
    // float -> bf16, round-to-nearest-even (inputs are finite normals)
    unsigned u = __float_as_uint(x);
    u += 0x7FFFu + ((u >> 16) & 1u);
    return (unsigned short)(u >> 16);
}

// Repack W1 (2052 x 64, row-major fp32) into bf16 MFMA B-fragment order:
// nt, kt, lane L, j:  B[k = kt*32 + (L>>4)*8 + j][n = nt*16 + (L&15)]
// flat: (((nt*KT_ + kt)*64 + L)*8 + j). Zero-pad k >= 2052.
__global__ void prep_w1(const float* __restrict__ W1, unsigned short* __restrict__ W1B) {
    const int blk  = blockIdx.x;            // 0 .. NT_*KT_-1
    const int nt   = blk / KT_;
    const int kt   = blk % KT_;
    const int lane = threadIdx.x;           // 64 threads
    const int n     = nt * 16 + (lane & 15);
    const int kbase = kt * 32 + (lane >> 4) * 8;
    unsigned short tmp[8];
#pragma unroll
    for (int j = 0; j < 8; ++j) {
        const int k = kbase + j;
        const float v = (k < (H_ + HINT_)) ? W1[(size_t)k * MLPH_ + n] : 0.0f;
        tmp[j] = f2b(v);
    }
    *(uint4*)(W1B + (((size_t)nt * KT_ + kt) * 64 + lane) * 8) = *(const uint4*)tmp;
}

__global__ __launch_bounds__(256) void wbh_kernel(
    const float* __restrict__ hidden,   // (B,S,H) fp32
    const int*   __restrict__ amask,    // (B,S) int32
    const float* __restrict__ hintf,    // (B,S,HINT) fp32
    const float* __restrict__ b1,       // (64)
    const float* __restrict__ W2,       // (64)
    const float* __restrict__ b2,       // (1)
    const unsigned short* __restrict__ W1B, // packed bf16 W1 fragments
    float* __restrict__ out)            // [0:4096) logits, [4096:8192) mask
{
    // 4 real window rows; MFMA A-lanes with m>=4 alias row m&3 (duplicate D
    // rows are never read). LDS total ~18.8 KB -> LDS allows 8 blocks/CU.
    __shared__ unsigned short pooledLds[WPB_ * LDK_];   // 17,472 B
    __shared__ float amLds[ROWS_];
    __shared__ float rinvLds[WPB_];
    __shared__ float partLds[WPB_ * PLD_];

    const int tid = threadIdx.x;
    const int bid = blockIdx.x;                    // 1024 blocks
    const int b     = bid >> 7;
    const int chunk = bid & 127;
    const int w0    = chunk * WPB_;
    const int s0    = chunk * (WPB_ * STRIDE_);

    // ---- Phase 0: zero k-pad cols (2052..2175) of the 4 rows; stage mask ----
    if (tid < WPB_ * 62) {                         // 62 uints x 4 rows
        const int row = tid / 62, cc = tid % 62;
        *(unsigned*)&pooledLds[row * LDK_ + 2052 + cc * 2] = 0u;
    }
    if (tid < ROWS_) {
        const int p = s0 + tid;
        amLds[tid] = (p < S_) ? (float)amask[b * S_ + p] : 0.0f;
    }
    __syncthreads();

    // ---- Phase 1a: denoms + window_mask output ----
    if (tid < WPB_) {
        float s = 0.f;
#pragma unroll
        for (int k = 0; k < WS_; ++k) s += amLds[tid * STRIDE_ + k];
        rinvLds[tid] = 1.0f / fmaxf(s, 1.0f);
        out[(size_t)(B_ * NW_) + (size_t)b * NW_ + w0 + tid] = (s > 0.f) ? 1.0f : 0.0f;
    }
    __syncthreads();

    // ---- Phase 1b: branch-free masked pooling, rolling 2-group window ----
    // Each thread covers cols [c0, c0+3] and [c0+1024, c0+1027].
    // am is exactly 0/1: select row pointer (masked row vs row 0, L1-hot) and
    // FMA by am — loads unconditional, 8 in flight per 4-row chunk.
    const int c0 = tid * 4;
    const float* rowBase = hidden + ((size_t)b * S_ + s0) * H_ + c0;

    floatx4 prevA = (floatx4){0.f,0.f,0.f,0.f}, prevB = prevA;
#pragma unroll
    for (int g = 0; g <= WPB_; ++g) {              // 5 groups of 8 rows
        floatx4 curA = (floatx4){0.f,0.f,0.f,0.f}, curB = curA;
#pragma unroll
        for (int kk = 0; kk < 2; ++kk) {           // 4-row chunks
            float am[4];
            const float* p[4];
#pragma unroll
            for (int k2 = 0; k2 < 4; ++k2) {
                const int rr = g * STRIDE_ + kk * 4 + k2;
                am[k2] = amLds[rr];
                p[k2]  = (am[k2] != 0.0f) ? (rowBase + (size_t)rr * H_) : rowBase;
            }
            floatx4 vA[4], vB[4];
#pragma unroll
            for (int k2 = 0; k2 < 4; ++k2) {
                vA[k2] = *(const floatx4*)(p[k2]);
                vB[k2] = *(const floatx4*)(p[k2] + 1024);
            }
#pragma unroll
            for (int k2 = 0; k2 < 4; ++k2) {
                curA.x = fmaf(am[k2], vA[k2].x, curA.x);
                curA.y = fmaf(am[k2], vA[k2].y, curA.y);
                curA.z = fmaf(am[k2], vA[k2].z, curA.z);
                curA.w = fmaf(am[k2], vA[k2].w, curA.w);
                curB.x = fmaf(am[k2], vB[k2].x, curB.x);
                curB.y = fmaf(am[k2], vB[k2].y, curB.y);
                curB.z = fmaf(am[k2], vB[k2].z, curB.z);
                curB.w = fmaf(am[k2], vB[k2].w, curB.w);
            }
        }
        if (g >= 1) {                              // finalize window w = g-1
            const int w = g - 1;
            const float r = rinvLds[w];
            const floatx4 sA = prevA + curA, sB = prevB + curB;
            unsigned short qA[4], qB[4];
            qA[0]=f2b(sA.x*r); qA[1]=f2b(sA.y*r); qA[2]=f2b(sA.z*r); qA[3]=f2b(sA.w*r);
            qB[0]=f2b(sB.x*r); qB[1]=f2b(sB.y*r); qB[2]=f2b(sB.z*r); qB[3]=f2b(sB.w*r);
            *(uint2*)(&pooledLds[w * LDK_ + c0])        = *(const uint2*)qA;
            *(uint2*)(&pooledLds[w * LDK_ + c0 + 1024]) = *(const uint2*)qB;
        }
        prevA = curA; prevB = curB;
    }

    if (tid < WPB_ * HINT_) {                      // hint pooling: 16 threads
        const int w = tid >> 2, hc = tid & 3;
        float s = 0.f;
#pragma unroll
        for (int k = 0; k < WS_; ++k) {
            const int rr = w * STRIDE_ + k;
            const float amv = amLds[rr];
            float hv = 0.f;
            if (amv != 0.0f)
                hv = hintf[((size_t)b * S_ + (s0 + rr)) * HINT_ + hc];
            s += amv * hv;
        }
        pooledLds[w * LDK_ + H_ + hc] = f2b(s * rinvLds[w]);
    }
    __syncthreads();

    // ---- Phase 2: MFMA (16x2176)@(2176x64); 4 waves = 4 n-tiles, full K ----
    const int wid  = tid >> 6;
    const int lane = tid & 63;
    {
        floatx4 dacc = (floatx4){0.f, 0.f, 0.f, 0.f};
        // A-frag: lane holds A[m=lane&15][k=kt*32+(lane>>4)*8+j]; row alias m&3
        const unsigned short* aBase = pooledLds + (lane & 3) * LDK_ + (lane >> 4) * 8;
        const unsigned short* bBase = W1B + ((size_t)wid * KT_ * 64 + lane) * 8;
#pragma unroll 4
        for (int kt = 0; kt < KT_; ++kt) {
            const shortx8 af = *(const shortx8*)(aBase + kt * 32);
            const shortx8 bf = *(const shortx8*)(bBase + (size_t)kt * 64 * 8);
            dacc = __builtin_amdgcn_mfma_f32_16x16x32_bf16(af, bf, dacc, 0, 0, 0);
        }
        // D: lane reg r holds D[row=(lane>>4)*4+r][col=lane&15]; rows>=4 dups.
        // Lanes 0..15 hold rows 0..3 in regs 0..3.
        if (lane < 16) {
            const int j = wid * 16 + lane;
#pragma unroll
            for (int r = 0; r < 4; ++r)
                partLds[r * PLD_ + j] = dacc[r];
        }
    }
    __syncthreads();

    // ---- Phase 3: wave m = window m; lane j; gelu + W2 + shuffle reduce ----
    {
        const int m = tid >> 6;                    // 4 waves = 4 windows
        const int j = tid & 63;
        const float a = partLds[m * PLD_ + j] + b1[j];
        float g = 0.5f * a * (1.0f + erff(a * 0.70710678118654752f)) * W2[j];
#pragma unroll
        for (int off = 32; off > 0; off >>= 1) g += __shfl_down(g, off, 64);
        if (j == 0) out[(size_t)b * NW_ + w0 + m] = g + b2[0];
    }
}

extern "C" void kernel_launch(void* const* d_in, const int* in_sizes, int n_in,
                              void* d_out, int out_size, void* d_ws, size_t ws_size,
                              hipStream_t stream) {
    const float* hidden = (const float*)d_in[0];
    const int*   amask  = (const int*)d_in[1];
    const float* hintf  = (const float*)d_in[2];
    const float* W1     = (const float*)d_in[3];
    const float* b1     = (const float*)d_in[4];
    const float* W2     = (const float*)d_in[5];
    const float* b2     = (const float*)d_in[6];
    float* out          = (float*)d_out;

    unsigned short* W1B = (unsigned short*)d_ws;   // NT_*KT_*64*8*2 = 278,528 B

    // d_ws is re-poisoned before every timed launch -> rebuild packed W1 every call
    prep_w1<<<NT_ * KT_, 64, 0, stream>>>(W1, W1B);
    wbh_kernel<<<B_ * (NW_ / WPB_), 256, 0, stream>>>(
        hidden, amask, hintf, b1, W2, b2, W1B, out);
}